// Round 1
// baseline (1506.958 us; speedup 1.0000x reference)
//
#include <hip/hip_runtime.h>
#include <cstdint>

#define F_DIM 128
#define TSTRIDE 33   // xs row stride in float4 (132 floats, pad avoids bank conflicts)
#define WSTRIDE 17   // W row stride in uint4  (68 uints = 136 bf16)

__device__ __forceinline__ uint32_t f2bf(float f){
    uint32_t u = __float_as_uint(f);
    return (u + 0x7FFFu + ((u >> 16) & 1u)) >> 16;   // RNE to bf16
}
__device__ __forceinline__ uint32_t packbf2(float lo, float hi){
    return f2bf(lo) | (f2bf(hi) << 16);
}
__device__ __forceinline__ float bf_lo(uint32_t u){ return __uint_as_float(u << 16); }
__device__ __forceinline__ float bf_hi(uint32_t u){ return __uint_as_float(u & 0xFFFF0000u); }

__device__ __forceinline__ float softplus_f(float v){
    return fmaxf(v, 0.f) + log1pf(__expf(-fabsf(v)));
}
__device__ __forceinline__ float silu_f(float v){
    return __fdividef(v, 1.f + __expf(-v));
}

// Stage a 128x128 fp32 weight matrix into LDS as bf16 pairs (packed in column pairs).
// w2[i*68 + c/2] holds cols (c, c+1) of row i.
__device__ __forceinline__ void fill_w(const float* __restrict__ W, uint32_t* w2, int tid){
    #pragma unroll
    for (int j = 0; j < 8; ++j){
        int f4 = tid + j*512;
        int i = f4 >> 5, c = f4 & 31;          // row i, float4-col c
        float4 w = ((const float4*)W)[i*32 + c];
        w2[i*68 + c*2 + 0] = packbf2(w.x, w.y);
        w2[i*68 + c*2 + 1] = packbf2(w.z, w.w);
    }
}

// acc[d][k] += sum_i xs[r0+d][i] * W[i][c0+k]   (c0 = 8*cg)
__device__ __forceinline__ void gemm_block(const float4* xs4, const uint4* w4,
                                           int r0, int cg, float acc[4][8]){
    #pragma unroll 8
    for (int i4 = 0; i4 < 32; ++i4){
        float4 xv[4];
        #pragma unroll
        for (int d = 0; d < 4; ++d) xv[d] = xs4[(r0 + d)*TSTRIDE + i4];
        uint4 wr[4];
        #pragma unroll
        for (int s = 0; s < 4; ++s) wr[s] = w4[(4*i4 + s)*WSTRIDE + cg];
        #pragma unroll
        for (int s = 0; s < 4; ++s){
            float wf[8];
            wf[0] = bf_lo(wr[s].x); wf[1] = bf_hi(wr[s].x);
            wf[2] = bf_lo(wr[s].y); wf[3] = bf_hi(wr[s].y);
            wf[4] = bf_lo(wr[s].z); wf[5] = bf_hi(wr[s].z);
            wf[6] = bf_lo(wr[s].w); wf[7] = bf_hi(wr[s].w);
            float xc[4];
            #pragma unroll
            for (int d = 0; d < 4; ++d) xc[d] = ((const float*)&xv[d])[s];
            #pragma unroll
            for (int d = 0; d < 4; ++d)
                #pragma unroll
                for (int k = 0; k < 8; ++k)
                    acc[d][k] = fmaf(xc[d], wf[k], acc[d][k]);
        }
    }
}

// K0: kb[b][f] = |E[b]|*Wk[f] + bk[f]; zero pred/natom (2B floats at `zeroed`)
__global__ void k_prep(const float* __restrict__ E, const float* __restrict__ Wk,
                       const float* __restrict__ bk, float* __restrict__ kb,
                       float* __restrict__ zeroed, int B){
    int gid = blockIdx.x*blockDim.x + threadIdx.x;
    if (gid < 2*B) zeroed[gid] = 0.f;
    if (gid < B*F_DIM){
        int b = gid >> 7, f = gid & 127;
        kb[gid] = fabsf(E[b]) * Wk[f] + bk[f];
    }
}

// K1: embed = softplus(kb[seg]*(x@Wq+bq)) -> out; rowsums -> pred; counts -> natom
__global__ void __launch_bounds__(512) k_embed(
    const float* __restrict__ x, const int* __restrict__ seg,
    const float* __restrict__ Wq, const float* __restrict__ bq,
    const float* __restrict__ kb, float* __restrict__ out,
    float* __restrict__ pred, float* __restrict__ natom, int N)
{
    __shared__ __align__(16) float xs[128*132];
    __shared__ __align__(16) uint32_t w2[128*68];
    float4* xs4w = (float4*)xs;
    const float4* xs4 = (const float4*)xs;
    const uint4* w4 = (const uint4*)w2;
    int tid = threadIdx.x;
    fill_w(Wq, w2, tid);
    int cg = tid & 15, rg = tid >> 4;
    int r0 = rg*4;
    float bias[8];
    {
        float4 b0 = ((const float4*)bq)[cg*2], b1 = ((const float4*)bq)[cg*2 + 1];
        bias[0]=b0.x; bias[1]=b0.y; bias[2]=b0.z; bias[3]=b0.w;
        bias[4]=b1.x; bias[5]=b1.y; bias[6]=b1.z; bias[7]=b1.w;
    }
    int lrow = tid >> 5, lc4 = tid & 31;
    int nt = (N + 127) >> 7;
    int tile = blockIdx.x;
    float4 xr[8];
    {
        int base = tile*128;
        #pragma unroll
        for (int j = 0; j < 8; ++j){
            int r = base + lrow + j*16;
            xr[j] = (tile < nt && r < N) ? ((const float4*)x)[(size_t)r*32 + lc4]
                                         : make_float4(0,0,0,0);
        }
    }
    for (; tile < nt; tile += gridDim.x){
        #pragma unroll
        for (int j = 0; j < 8; ++j) xs4w[(lrow + j*16)*TSTRIDE + lc4] = xr[j];
        __syncthreads();
        int ntile = tile + gridDim.x;
        if (ntile < nt){
            int base = ntile*128;
            #pragma unroll
            for (int j = 0; j < 8; ++j){
                int r = base + lrow + j*16;
                xr[j] = (r < N) ? ((const float4*)x)[(size_t)r*32 + lc4]
                                : make_float4(0,0,0,0);
            }
        }
        float acc[4][8];
        #pragma unroll
        for (int d = 0; d < 4; ++d)
            #pragma unroll
            for (int k = 0; k < 8; ++k) acc[d][k] = bias[k];
        gemm_block(xs4, w4, r0, cg, acc);
        int base = tile*128;
        #pragma unroll
        for (int d = 0; d < 4; ++d){
            int r = base + r0 + d;
            if (r < N){                        // uniform across the 16-lane cg group
                int s = seg[r];
                float4 k0 = ((const float4*)kb)[(size_t)s*32 + cg*2];
                float4 k1 = ((const float4*)kb)[(size_t)s*32 + cg*2 + 1];
                float kv[8] = {k0.x,k0.y,k0.z,k0.w,k1.x,k1.y,k1.z,k1.w};
                float e[8]; float rs = 0.f;
                #pragma unroll
                for (int k = 0; k < 8; ++k){ e[k] = softplus_f(kv[k]*acc[d][k]); rs += e[k]; }
                ((float4*)out)[(size_t)r*32 + cg*2]     = make_float4(e[0],e[1],e[2],e[3]);
                ((float4*)out)[(size_t)r*32 + cg*2 + 1] = make_float4(e[4],e[5],e[6],e[7]);
                #pragma unroll
                for (int m = 8; m >= 1; m >>= 1) rs += __shfl_xor(rs, m, 16);
                if (cg == 0){
                    atomicAdd(&pred[s], rs);
                    atomicAdd(&natom[s], 1.f);
                }
            }
        }
        __syncthreads();
    }
}

// K2: dsc[b] = (E[b]-pred[b])/natom[b]/F
__global__ void k_dsc(const float* __restrict__ E, const float* __restrict__ pred,
                      const float* __restrict__ natom, float* __restrict__ dsc, int B){
    int b = blockIdx.x*blockDim.x + threadIdx.x;
    if (b < B) dsc[b] = (E[b] - pred[b]) / natom[b] * (1.0f/128.0f);
}

// K3: se = embed + dsc[seg]; out = se + (silu(silu(se)@W1+b1)@W2+b2)   (in place on d_out)
__global__ void __launch_bounds__(512) k_resid(
    const int* __restrict__ seg, const float* __restrict__ dsc,
    const float* __restrict__ W1, const float* __restrict__ b1,
    const float* __restrict__ W2, const float* __restrict__ b2,
    float* __restrict__ out, int N)
{
    __shared__ __align__(16) float xs[128*132];
    __shared__ __align__(16) uint32_t w2a[128*68];
    __shared__ __align__(16) uint32_t w2b[128*68];
    float4* xs4w = (float4*)xs;
    const float4* xs4 = (const float4*)xs;
    const uint4* w4a = (const uint4*)w2a;
    const uint4* w4b = (const uint4*)w2b;
    int tid = threadIdx.x;
    fill_w(W1, w2a, tid);
    fill_w(W2, w2b, tid);
    int cg = tid & 15, rg = tid >> 4;
    int r0 = rg*4;
    float bias1[8], bias2[8];
    {
        float4 a0 = ((const float4*)b1)[cg*2], a1 = ((const float4*)b1)[cg*2 + 1];
        bias1[0]=a0.x; bias1[1]=a0.y; bias1[2]=a0.z; bias1[3]=a0.w;
        bias1[4]=a1.x; bias1[5]=a1.y; bias1[6]=a1.z; bias1[7]=a1.w;
        float4 c0v = ((const float4*)b2)[cg*2], c1v = ((const float4*)b2)[cg*2 + 1];
        bias2[0]=c0v.x; bias2[1]=c0v.y; bias2[2]=c0v.z; bias2[3]=c0v.w;
        bias2[4]=c1v.x; bias2[5]=c1v.y; bias2[6]=c1v.z; bias2[7]=c1v.w;
    }
    int lrow = tid >> 5, lc4 = tid & 31;
    int nt = (N + 127) >> 7;
    int tile = blockIdx.x;
    float4 er[8];
    {
        int base = tile*128;
        #pragma unroll
        for (int j = 0; j < 8; ++j){
            int r = base + lrow + j*16;
            er[j] = (tile < nt && r < N) ? ((const float4*)out)[(size_t)r*32 + lc4]
                                         : make_float4(0,0,0,0);
        }
    }
    for (; tile < nt; tile += gridDim.x){
        int base = tile*128;
        // stage t1 = silu(embed + dsc[seg]) into xs
        #pragma unroll
        for (int j = 0; j < 8; ++j){
            int r = base + lrow + j*16;
            if (r < N){
                int s = seg[r];
                float dv = dsc[s];
                float4 t;
                t.x = silu_f(er[j].x + dv); t.y = silu_f(er[j].y + dv);
                t.z = silu_f(er[j].z + dv); t.w = silu_f(er[j].w + dv);
                xs4w[(lrow + j*16)*TSTRIDE + lc4] = t;
            }
        }
        __syncthreads();
        int ntile = tile + gridDim.x;
        if (ntile < nt){
            int nbase = ntile*128;
            #pragma unroll
            for (int j = 0; j < 8; ++j){
                int r = nbase + lrow + j*16;
                er[j] = (r < N) ? ((const float4*)out)[(size_t)r*32 + lc4]
                                : make_float4(0,0,0,0);
            }
        }
        float acc[4][8];
        #pragma unroll
        for (int d = 0; d < 4; ++d)
            #pragma unroll
            for (int k = 0; k < 8; ++k) acc[d][k] = bias1[k];
        gemm_block(xs4, w4a, r0, cg, acc);
        float t2[4][8];
        #pragma unroll
        for (int d = 0; d < 4; ++d)
            #pragma unroll
            for (int k = 0; k < 8; ++k) t2[d][k] = silu_f(acc[d][k]);
        __syncthreads();     // all reads of t1 done
        #pragma unroll
        for (int d = 0; d < 4; ++d){
            xs4w[(r0 + d)*TSTRIDE + cg*2]     = make_float4(t2[d][0],t2[d][1],t2[d][2],t2[d][3]);
            xs4w[(r0 + d)*TSTRIDE + cg*2 + 1] = make_float4(t2[d][4],t2[d][5],t2[d][6],t2[d][7]);
        }
        __syncthreads();
        float acc2[4][8];
        #pragma unroll
        for (int d = 0; d < 4; ++d)
            #pragma unroll
            for (int k = 0; k < 8; ++k) acc2[d][k] = bias2[k];
        gemm_block(xs4, w4b, r0, cg, acc2);
        // epilogue: out = (embed + dsc) + h2   (re-read embed, L2-hot; in-place per thread)
        #pragma unroll
        for (int d = 0; d < 4; ++d){
            int r = base + r0 + d;
            if (r < N){
                int s = seg[r];
                float dv = dsc[s];
                float4 e0 = ((const float4*)out)[(size_t)r*32 + cg*2];
                float4 e1 = ((const float4*)out)[(size_t)r*32 + cg*2 + 1];
                float4 o0, o1;
                o0.x = e0.x + dv + acc2[d][0]; o0.y = e0.y + dv + acc2[d][1];
                o0.z = e0.z + dv + acc2[d][2]; o0.w = e0.w + dv + acc2[d][3];
                o1.x = e1.x + dv + acc2[d][4]; o1.y = e1.y + dv + acc2[d][5];
                o1.z = e1.z + dv + acc2[d][6]; o1.w = e1.w + dv + acc2[d][7];
                ((float4*)out)[(size_t)r*32 + cg*2]     = o0;
                ((float4*)out)[(size_t)r*32 + cg*2 + 1] = o1;
            }
        }
        __syncthreads();
    }
}

extern "C" void kernel_launch(void* const* d_in, const int* in_sizes, int n_in,
                              void* d_out, int out_size, void* d_ws, size_t ws_size,
                              hipStream_t stream)
{
    const float* x  = (const float*)d_in[0];
    const float* E  = (const float*)d_in[1];
    const int*  seg = (const int*)d_in[3];
    const float* Wq = (const float*)d_in[4];
    const float* bq = (const float*)d_in[5];
    const float* Wk = (const float*)d_in[6];
    const float* bk = (const float*)d_in[7];
    const float* W1 = (const float*)d_in[8];
    const float* b1 = (const float*)d_in[9];
    const float* W2 = (const float*)d_in[10];
    const float* b2 = (const float*)d_in[11];
    float* out = (float*)d_out;
    int N = in_sizes[0] / F_DIM;
    int B = in_sizes[1];

    float* kb    = (float*)d_ws;             // [B,128]
    float* pred  = kb + (size_t)B*F_DIM;     // [B]
    float* natom = pred + B;                 // [B]
    float* dsc   = natom + B;                // [B]

    hipLaunchKernelGGL(k_prep, dim3((B*F_DIM + 255)/256), dim3(256), 0, stream,
                       E, Wk, bk, kb, pred, B);
    hipLaunchKernelGGL(k_embed, dim3(256), dim3(512), 0, stream,
                       x, seg, Wq, bq, kb, out, pred, natom, N);
    hipLaunchKernelGGL(k_dsc, dim3((B + 255)/256), dim3(256), 0, stream,
                       E, pred, natom, dsc, B);
    hipLaunchKernelGGL(k_resid, dim3(256), dim3(512), 0, stream,
                       seg, dsc, W1, b1, W2, b2, out, N);
}

// Round 2
// 1088.705 us; speedup vs baseline: 1.3842x; 1.3842x over previous
//
#include <hip/hip_runtime.h>
#include <cstdint>

#define F_DIM 128
#define XSTR 136   // shorts per LDS row: 128 + 8 pad -> row stride 272 B (17x16B), 2-way banks (free)

typedef short s16x8 __attribute__((ext_vector_type(8)));
typedef float f32x4 __attribute__((ext_vector_type(4)));

__device__ __forceinline__ uint32_t f2bf(float f){
    uint32_t u = __float_as_uint(f);
    return (u + 0x7FFFu + ((u >> 16) & 1u)) >> 16;   // RNE
}
__device__ __forceinline__ uint32_t packbf2(float lo, float hi){
    return f2bf(lo) | (f2bf(hi) << 16);
}
__device__ __forceinline__ uint2 cvt4(float4 v){
    return make_uint2(packbf2(v.x, v.y), packbf2(v.z, v.w));
}
__device__ __forceinline__ float softplus_f(float v){
    return fmaxf(v, 0.f) + log1pf(__expf(-fabsf(v)));
}
__device__ __forceinline__ float silu_f(float v){
    return __fdividef(v, 1.f + __expf(-v));
}

// K0: kb[b][f] = |E[b]|*Wk[f] + bk[f]; zero pred/natom (2B floats at `zeroed`)
__global__ void k_prep(const float* __restrict__ E, const float* __restrict__ Wk,
                       const float* __restrict__ bk, float* __restrict__ kb,
                       float* __restrict__ zeroed, int B){
    int gid = blockIdx.x*blockDim.x + threadIdx.x;
    if (gid < 2*B) zeroed[gid] = 0.f;
    if (gid < B*F_DIM){
        int b = gid >> 7, f = gid & 127;
        kb[gid] = fabsf(E[b]) * Wk[f] + bk[f];
    }
}

// K1: embed = softplus(kb[seg]*(x@Wq+bq)) -> out; rowsums -> pred; counts -> natom
// 8 waves, wave w owns output cols [16w,16w+16); Wq strip in registers.
__global__ void __launch_bounds__(512, 4) k_embed(
    const float* __restrict__ x, const int* __restrict__ seg,
    const float* __restrict__ Wq, const float* __restrict__ bq,
    const float* __restrict__ kb, float* __restrict__ out,
    float* __restrict__ pred, float* __restrict__ natom, int N)
{
    __shared__ __align__(16) short xs[128*XSTR];
    __shared__ float rs[128];
    const int tid  = threadIdx.x;
    const int wave = tid >> 6, lane = tid & 63;
    const int quad = lane >> 4, ln = lane & 15;
    const int mycol = wave*16 + ln;

    // B fragments: B[k][n], n = lane&15, k = quad*8+j within each K=32 step
    s16x8 wf[4];
    #pragma unroll
    for (int s = 0; s < 4; ++s)
        #pragma unroll
        for (int j = 0; j < 8; ++j)
            wf[s][j] = (short)f2bf(Wq[(size_t)(s*32 + quad*8 + j)*F_DIM + mycol]);
    const float biasv = bq[mycol];

    const int lrow = tid >> 5, lc4 = tid & 31;
    const int nt = (N + 127) >> 7;
    for (int tile = blockIdx.x; tile < nt; tile += gridDim.x){
        const int base = tile << 7;
        // stage x tile -> bf16 LDS (coalesced float4 reads, uint2 LDS writes)
        #pragma unroll
        for (int j = 0; j < 8; ++j){
            int rr = lrow + j*16;
            int r = base + rr;
            if (r < N){
                float4 v = ((const float4*)x)[(size_t)r*32 + lc4];
                *(uint2*)&xs[rr*XSTR + lc4*4] = cvt4(v);
            }
        }
        if (tid < 128) rs[tid] = 0.f;
        __syncthreads();

        #pragma unroll
        for (int rt = 0; rt < 8; ++rt){
            f32x4 acc = {0.f, 0.f, 0.f, 0.f};
            #pragma unroll
            for (int s = 0; s < 4; ++s){
                // A[m][k]: m = ln, k = quad*8+j  (16B-aligned ds_read_b128)
                s16x8 a = *(const s16x8*)&xs[(rt*16 + ln)*XSTR + s*32 + quad*8];
                acc = __builtin_amdgcn_mfma_f32_16x16x32_bf16(a, wf[s], acc, 0, 0, 0);
            }
            #pragma unroll
            for (int reg = 0; reg < 4; ++reg){
                int r = base + rt*16 + quad*4 + reg;   // D: row = quad*4+reg, col = ln
                if (r < N){
                    int sgi = seg[r];
                    float kv = kb[(size_t)sgi*F_DIM + mycol];
                    float e = softplus_f(kv * (acc[reg] + biasv));
                    out[(size_t)r*F_DIM + mycol] = e;
                    float p = e;   // reduce the 16 cols this wave holds for row r
                    #pragma unroll
                    for (int m = 8; m >= 1; m >>= 1) p += __shfl_xor(p, m, 16);
                    if (ln == 0) atomicAdd(&rs[rt*16 + quad*4 + reg], p);
                }
            }
        }
        __syncthreads();
        if (tid < 128){
            int r = base + tid;
            if (r < N){
                int sgi = seg[r];
                atomicAdd(&pred[sgi], rs[tid]);
                atomicAdd(&natom[sgi], 1.f);
            }
        }
        __syncthreads();
    }
}

// K2: dsc[b] = (E[b]-pred[b])/natom[b]/F
__global__ void k_dsc(const float* __restrict__ E, const float* __restrict__ pred,
                      const float* __restrict__ natom, float* __restrict__ dsc, int B){
    int b = blockIdx.x*blockDim.x + threadIdx.x;
    if (b < B) dsc[b] = (E[b] - pred[b]) / natom[b] * (1.0f/128.0f);
}

// K3: se = embed + dsc[seg]; out = se + (silu(silu(se)@W1+b1)@W2+b2)  (in place on d_out)
__global__ void __launch_bounds__(512, 4) k_resid(
    const int* __restrict__ seg, const float* __restrict__ dsc,
    const float* __restrict__ W1, const float* __restrict__ b1,
    const float* __restrict__ W2, const float* __restrict__ b2,
    float* __restrict__ out, int N)
{
    __shared__ __align__(16) short xs[128*XSTR];   // t1 = silu(se), bf16
    __shared__ __align__(16) short t2[128*XSTR];   // t2 = silu(h1), bf16
    const int tid  = threadIdx.x;
    const int wave = tid >> 6, lane = tid & 63;
    const int quad = lane >> 4, ln = lane & 15;
    const int mycol = wave*16 + ln;

    s16x8 w1f[4], w2f[4];
    #pragma unroll
    for (int s = 0; s < 4; ++s)
        #pragma unroll
        for (int j = 0; j < 8; ++j){
            int k = s*32 + quad*8 + j;
            w1f[s][j] = (short)f2bf(W1[(size_t)k*F_DIM + mycol]);
            w2f[s][j] = (short)f2bf(W2[(size_t)k*F_DIM + mycol]);
        }
    const float b1v = b1[mycol], b2v = b2[mycol];

    const int lrow = tid >> 5, lc4 = tid & 31;
    const int nt = (N + 127) >> 7;
    for (int tile = blockIdx.x; tile < nt; tile += gridDim.x){
        const int base = tile << 7;
        // stage t1 = silu(embed + dsc[seg]) -> bf16 LDS
        #pragma unroll
        for (int j = 0; j < 8; ++j){
            int rr = lrow + j*16;
            int r = base + rr;
            if (r < N){
                int s0 = seg[r];
                float dv = dsc[s0];
                float4 v = ((const float4*)out)[(size_t)r*32 + lc4];
                float4 t;
                t.x = silu_f(v.x + dv); t.y = silu_f(v.y + dv);
                t.z = silu_f(v.z + dv); t.w = silu_f(v.w + dv);
                *(uint2*)&xs[rr*XSTR + lc4*4] = cvt4(t);
            }
        }
        __syncthreads();

        // GEMM1 + silu -> t2 (bf16 LDS)
        #pragma unroll
        for (int rt = 0; rt < 8; ++rt){
            f32x4 acc = {0.f, 0.f, 0.f, 0.f};
            #pragma unroll
            for (int s = 0; s < 4; ++s){
                s16x8 a = *(const s16x8*)&xs[(rt*16 + ln)*XSTR + s*32 + quad*8];
                acc = __builtin_amdgcn_mfma_f32_16x16x32_bf16(a, w1f[s], acc, 0, 0, 0);
            }
            #pragma unroll
            for (int reg = 0; reg < 4; ++reg){
                int row = rt*16 + quad*4 + reg;
                float h = silu_f(acc[reg] + b1v);
                t2[row*XSTR + mycol] = (short)f2bf(h);
            }
        }
        __syncthreads();

        // GEMM2 + residual epilogue (re-read embed from global, L2-hot)
        #pragma unroll
        for (int rt = 0; rt < 8; ++rt){
            f32x4 acc = {0.f, 0.f, 0.f, 0.f};
            #pragma unroll
            for (int s = 0; s < 4; ++s){
                s16x8 a = *(const s16x8*)&t2[(rt*16 + ln)*XSTR + s*32 + quad*8];
                acc = __builtin_amdgcn_mfma_f32_16x16x32_bf16(a, w2f[s], acc, 0, 0, 0);
            }
            #pragma unroll
            for (int reg = 0; reg < 4; ++reg){
                int r = base + rt*16 + quad*4 + reg;
                if (r < N){
                    int s0 = seg[r];
                    float dv = dsc[s0];
                    float se = out[(size_t)r*F_DIM + mycol] + dv;
                    out[(size_t)r*F_DIM + mycol] = se + acc[reg] + b2v;
                }
            }
        }
        __syncthreads();
    }
}

extern "C" void kernel_launch(void* const* d_in, const int* in_sizes, int n_in,
                              void* d_out, int out_size, void* d_ws, size_t ws_size,
                              hipStream_t stream)
{
    const float* x  = (const float*)d_in[0];
    const float* E  = (const float*)d_in[1];
    const int*  seg = (const int*)d_in[3];
    const float* Wq = (const float*)d_in[4];
    const float* bq = (const float*)d_in[5];
    const float* Wk = (const float*)d_in[6];
    const float* bk = (const float*)d_in[7];
    const float* W1 = (const float*)d_in[8];
    const float* b1 = (const float*)d_in[9];
    const float* W2 = (const float*)d_in[10];
    const float* b2 = (const float*)d_in[11];
    float* out = (float*)d_out;
    int N = in_sizes[0] / F_DIM;
    int B = in_sizes[1];

    float* kb    = (float*)d_ws;             // [B,128]
    float* pred  = kb + (size_t)B*F_DIM;     // [B]
    float* natom = pred + B;                 // [B]
    float* dsc   = natom + B;                // [B]

    hipLaunchKernelGGL(k_prep, dim3((B*F_DIM + 255)/256), dim3(256), 0, stream,
                       E, Wk, bk, kb, pred, B);
    hipLaunchKernelGGL(k_embed, dim3(512), dim3(512), 0, stream,
                       x, seg, Wq, bq, kb, out, pred, natom, N);
    hipLaunchKernelGGL(k_dsc, dim3((B + 255)/256), dim3(256), 0, stream,
                       E, pred, natom, dsc, B);
    hipLaunchKernelGGL(k_resid, dim3(512), dim3(512), 0, stream,
                       seg, dsc, W1, b1, W2, b2, out, N);
}